// Round 3
// baseline (511.065 us; speedup 1.0000x reference)
//
#include <hip/hip_runtime.h>
#include <hip/hip_bf16.h>
#include <cstddef>
#include <cstdint>

typedef _Float16 half2_t __attribute__((ext_vector_type(2)));

#define C_CH   384
#define HW     56
#define PLANE  3136
#define KK     31
#define NPAIR  16            // 16 half2 weight pairs per kernel row (pair 15 = (w30, 0))
#define LROWS  86            // 56 + 2*15 halo rows
#define LSTW   52            // LDS row stride in dwords (104 halfs); 364 = 7*52 ≡ 12 mod 32 -> quad spread
#define LDS_DW (LROWS * LSTW)   // 4472 dwords = 17.9 KB

static __device__ __forceinline__ uint32_t pack_h2(float a, float b) {
    return __builtin_bit_cast(uint32_t, __builtin_amdgcn_cvt_pkrtz(a, b));
}
static __device__ __forceinline__ half2_t as_h2(uint32_t u) {
    return __builtin_bit_cast(half2_t, u);
}

// ---------------- weight merge + BN fold + f16 pair packing ----------------
__global__ void prep_weights(const float* __restrict__ lk_w,
                             const float* __restrict__ lk_g, const float* __restrict__ lk_b,
                             const float* __restrict__ lk_m, const float* __restrict__ lk_v,
                             const float* __restrict__ sk_w,
                             const float* __restrict__ sk_g, const float* __restrict__ sk_b,
                             const float* __restrict__ sk_m, const float* __restrict__ sk_v,
                             uint32_t* __restrict__ wpk, float* __restrict__ bias) {
    const int c = blockIdx.x;
    const float s1 = lk_g[c] / sqrtf(lk_v[c] + 1e-5f);
    const float s2 = sk_g[c] / sqrtf(sk_v[c] + 1e-5f);
    if (threadIdx.x == 0)
        bias[c] = (lk_b[c] - lk_m[c] * s1) + (sk_b[c] - sk_m[c] * s2);

    auto merged = [&](int ky, int kx) -> float {
        float w = lk_w[c * (KK*KK) + ky * KK + kx] * s1;
        if (ky >= 13 && ky <= 17 && kx >= 13 && kx <= 17)
            w += sk_w[c * 25 + (ky - 13) * 5 + (kx - 13)] * s2;
        return w;
    };

    for (int i = threadIdx.x; i < KK * NPAIR; i += blockDim.x) {
        const int ky = i / NPAIR, m = i - ky * NPAIR;
        const int kx0 = 2 * m;
        const float w0 = merged(ky, kx0);
        const float w1 = (kx0 + 1 < KK) ? merged(ky, kx0 + 1) : 0.f;
        wpk[c * (KK*NPAIR) + i] = pack_h2(w0, w1);
    }
}

// ---------------- merged 31x31 depthwise conv, f16 dot2, 7x8 tiles ----------------
// __launch_bounds__(64, 2): 1-wave block, min 2 waves/EU -> 256-VGPR budget.
// Without this the compiler targets 8 waves/EU (64 VGPRs) and demotes the
// re[]/ro[] row window out of registers -> per-operand LDS reads -> LDS-pipe
// bound (R2: 431us @ VGPR=68). Occupancy is LDS-limited (17.9KB -> 8 blk/CU
// = 2 waves/SIMD) so the higher VGPR count costs nothing.
__global__ __launch_bounds__(64, 2) void dwconv31(const float* __restrict__ x,
                                                  const uint32_t* __restrict__ wpk,
                                                  const float* __restrict__ bias,
                                                  float* __restrict__ out) {
    __shared__ uint32_t ldsw[LDS_DW];   // f16 plane, halo-padded; half h = global col h-16

    const int plane = blockIdx.x;       // n*384 + c
    const int c = plane % C_CH;
    const int tid = threadIdx.x;
    const float* __restrict__ xp = x + (size_t)plane * PLANE;

    // zero-fill (halo), then stage interior as packed f16
    {
        uint4 z = make_uint4(0u, 0u, 0u, 0u);
        uint4* l4 = (uint4*)ldsw;
        for (int i = tid; i < LDS_DW / 4; i += 64) l4[i] = z;
    }
    __syncthreads();
    {
        const float4* xp4 = (const float4*)xp;
        for (int i = tid; i < (HW * HW) / 4; i += 64) {   // 784 float4
            const int r = i / 14, q = i - r * 14;          // row r, cols 4q..4q+3
            float4 v = xp4[i];
            uint2 h;
            h.x = pack_h2(v.x, v.y);
            h.y = pack_h2(v.z, v.w);
            *(uint2*)&ldsw[(15 + r) * LSTW + 8 + 2 * q] = h;
        }
    }
    __syncthreads();

    if (tid >= 56) return;
    const int rt = tid / 7;             // 8 row-tiles of 7
    const int tx = tid - rt * 7;        // 7 col-tiles of 8
    const int r0 = rt * 7;
    const uint32_t* __restrict__ wc = wpk + c * (KK * NPAIR);

    float acc[7][8];
    #pragma unroll
    for (int j = 0; j < 7; ++j)
        #pragma unroll
        for (int i = 0; i < 8; ++i) acc[j][i] = 0.f;

    // input rows r0 .. r0+36; window halfs cover global cols 8tx-16 .. 8tx+23
    #pragma unroll 1
    for (int iy = 0; iy < 37; ++iy) {
        uint32_t re[20];
        {
            const uint4* lp = (const uint4*)&ldsw[(r0 + iy) * LSTW + 4 * tx];
            #pragma unroll
            for (int u = 0; u < 5; ++u) {
                uint4 t = lp[u];
                re[4*u + 0] = t.x; re[4*u + 1] = t.y;
                re[4*u + 2] = t.z; re[4*u + 3] = t.w;
            }
        }
        uint32_t ro[19];
        #pragma unroll
        for (int j2 = 0; j2 < 19; ++j2)
            ro[j2] = (re[j2] >> 16) | (re[j2 + 1] << 16);   // elements (2j+1, 2j+2) -> v_alignbit

        const int jlo = (iy - 30 < 0) ? 0 : iy - 30;
        const int jhi = (iy < 6) ? iy : 6;

        #pragma unroll
        for (int j = 0; j < 7; ++j) {
            if (j < jlo || j > jhi) continue;               // uniform branch
            const uint32_t* __restrict__ wrow = wc + (iy - j) * NPAIR;
            #pragma unroll
            for (int m = 0; m < NPAIR; ++m) {
                const half2_t w2 = as_h2(wrow[m]);
                // out col i, tap pair kx=(2m,2m+1) -> window elems (i+2m+1, i+2m+2)
                acc[j][0] = __builtin_amdgcn_fdot2(as_h2(ro[m    ]), w2, acc[j][0], false);
                acc[j][1] = __builtin_amdgcn_fdot2(as_h2(re[1 + m]), w2, acc[j][1], false);
                acc[j][2] = __builtin_amdgcn_fdot2(as_h2(ro[1 + m]), w2, acc[j][2], false);
                acc[j][3] = __builtin_amdgcn_fdot2(as_h2(re[2 + m]), w2, acc[j][3], false);
                acc[j][4] = __builtin_amdgcn_fdot2(as_h2(ro[2 + m]), w2, acc[j][4], false);
                acc[j][5] = __builtin_amdgcn_fdot2(as_h2(re[3 + m]), w2, acc[j][5], false);
                acc[j][6] = __builtin_amdgcn_fdot2(as_h2(ro[3 + m]), w2, acc[j][6], false);
                acc[j][7] = __builtin_amdgcn_fdot2(as_h2(re[4 + m]), w2, acc[j][7], false);
            }
        }
    }

    const float b = bias[c];
    float* __restrict__ op = out + (size_t)plane * PLANE;
    #pragma unroll
    for (int j = 0; j < 7; ++j) {
        float4 o0 = { acc[j][0] + b, acc[j][1] + b, acc[j][2] + b, acc[j][3] + b };
        float4 o1 = { acc[j][4] + b, acc[j][5] + b, acc[j][6] + b, acc[j][7] + b };
        float4* dst = (float4*)&op[(r0 + j) * HW + 8 * tx];
        dst[0] = o0;
        dst[1] = o1;
    }
}

extern "C" void kernel_launch(void* const* d_in, const int* in_sizes, int n_in,
                              void* d_out, int out_size, void* d_ws, size_t ws_size,
                              hipStream_t stream) {
    const float* x    = (const float*)d_in[0];
    const float* lk_w = (const float*)d_in[1];
    const float* lk_g = (const float*)d_in[2];
    const float* lk_b = (const float*)d_in[3];
    const float* lk_m = (const float*)d_in[4];
    const float* lk_v = (const float*)d_in[5];
    const float* sk_w = (const float*)d_in[6];
    const float* sk_g = (const float*)d_in[7];
    const float* sk_b = (const float*)d_in[8];
    const float* sk_m = (const float*)d_in[9];
    const float* sk_v = (const float*)d_in[10];
    float* out = (float*)d_out;

    uint32_t* wpk = (uint32_t*)d_ws;                  // 384*31*16 dwords = 762 KB
    float* bias   = (float*)(wpk + C_CH * KK * NPAIR);

    prep_weights<<<C_CH, 64, 0, stream>>>(lk_w, lk_g, lk_b, lk_m, lk_v,
                                          sk_w, sk_g, sk_b, sk_m, sk_v,
                                          wpk, bias);

    dwconv31<<<16 * C_CH, 64, 0, stream>>>(x, wpk, bias, out);
}

// Round 5
// 247.636 us; speedup vs baseline: 2.0638x; 2.0638x over previous
//
#include <hip/hip_runtime.h>
#include <cstdint>
#include <cstddef>

#define C_CH  384
#define HW    56
#define PLANE 3136
#define KK    31
#define PAD   15

typedef _Float16 f16x8 __attribute__((ext_vector_type(8)));
typedef float    f32x16 __attribute__((ext_vector_type(16)));
typedef uint32_t u32x4 __attribute__((ext_vector_type(4)));
typedef uint64_t u64x2 __attribute__((ext_vector_type(2)));

// LDS geometry (bytes). Plane rows are 256B (128 halfs) so the XOR swizzle
// (bits 4-6) can never escape the row (R4 bug: 176B stride + XOR crossed rows
// -> staging collisions -> absmax 3.1).
#define ROWB   256
#define NROWS  94                  // rows 0..85 = padded image, 86..93 zero (h>=56 discard)
#define PLSZ   (NROWS*ROWB)        // 24064 per plane
#define WE_OFF (2*PLSZ)            // even-shift weight copy: [31 ky][96 halfs]
#define WO_OFF (WE_OFF + 31*192)   // odd-shift copy (shifted by 1 half)
#define LDS_BYTES (WO_OFF + 31*192)  // 60032 < 64KB

static __device__ __forceinline__ uint32_t pack_h2(float a, float b) {
    return __builtin_bit_cast(uint32_t, __builtin_amdgcn_cvt_pkrtz(a, b));
}

// ---------------- weight merge + BN fold (fp32, stride-32 rows) ----------------
__global__ void prep_weights(const float* __restrict__ lk_w,
                             const float* __restrict__ lk_g, const float* __restrict__ lk_b,
                             const float* __restrict__ lk_m, const float* __restrict__ lk_v,
                             const float* __restrict__ sk_w,
                             const float* __restrict__ sk_g, const float* __restrict__ sk_b,
                             const float* __restrict__ sk_m, const float* __restrict__ sk_v,
                             float* __restrict__ wm, float* __restrict__ bias) {
    const int c = blockIdx.x;
    const float s1 = lk_g[c] / sqrtf(lk_v[c] + 1e-5f);
    const float s2 = sk_g[c] / sqrtf(sk_v[c] + 1e-5f);
    if (threadIdx.x == 0)
        bias[c] = (lk_b[c] - lk_m[c] * s1) + (sk_b[c] - sk_m[c] * s2);
    for (int i = threadIdx.x; i < KK * 32; i += blockDim.x) {
        const int ky = i >> 5, kx = i & 31;
        float w = 0.f;
        if (kx < KK) {
            w = lk_w[c * (KK*KK) + ky * KK + kx] * s1;
            if (ky >= 13 && ky <= 17 && kx >= 13 && kx <= 17)
                w += sk_w[c * 25 + (ky - 13) * 5 + (kx - 13)] * s2;
        }
        wm[c * (KK*32) + i] = w;
    }
}

// ---------------- merged 31x31 depthwise conv via MFMA Toeplitz GEMM ----------------
// Block = (channel c, 2 batch planes). Per ky:
//   Out[m, w] += A[m, j] * B[j, w],  A[m,j] = X_pad[h(m)+ky, j],
//   B[j, w] = Wm[ky, j-w-1]  (Toeplitz band; zero outside [0,30]).
// M = 32 = 2 planes x 16 h-rows; h-tiles {0,16,32,48}; N-tiles {0,32}.
// 4 waves = (wt, hp); wave owns h-tiles {2hp, 2hp+1} x w-tile wt.
// A fragment: m = lane&31, k = 8*(lane>>5)+e (one swizzled ds_read_b128).
// B fragment: n = lane&31, k = 8*(lane>>5)+e, from 2 shifted weight copies so
// any 8-half window is dword-aligned.
__global__ __launch_bounds__(256, 2) void dw31_mfma(const float* __restrict__ x,
                                                    const float* __restrict__ wm,
                                                    const float* __restrict__ bias,
                                                    float* __restrict__ out) {
    __shared__ __align__(16) uint8_t lds8[LDS_BYTES];
    const int c  = blockIdx.x;
    const int ng = blockIdx.y;            // batch pair: planes n = 2*ng + {0,1}
    const int tid = threadIdx.x;
    const int wid = tid >> 6, lane = tid & 63;
    const int wt = wid & 1, hp = wid >> 1;
    const int col = lane & 31, hi = lane >> 5;

    // ---- zero LDS ----
    {
        uint4 z = make_uint4(0u,0u,0u,0u);
        uint4* p = (uint4*)lds8;
        for (int i = tid; i < LDS_BYTES/16; i += 256) p[i] = z;
    }
    __syncthreads();

    // ---- stage 2 planes f32 -> f16 (swizzled); LDS col j = x col (j-16), row rl = x row (rl-15) ----
    for (int i = tid; i < 2*784; i += 256) {
        const int nn = (i >= 784);
        const int ii = i - nn*784;
        const int r = ii / 14, q = ii - r*14;      // x row r, cols 4q..4q+3
        const float4 v = ((const float4*)(x + ((size_t)((ng*2+nn)*C_CH + c))*PLANE))[ii];
        const int rl = r + PAD;
        int byte0 = nn*PLSZ + rl*ROWB + 2*(16 + 4*q);
        byte0 ^= (rl & 14) << 3;                   // bits 4-6 only: stays in-row, keeps 8B blocks
        uint2 h;
        h.x = pack_h2(v.x, v.y);
        h.y = pack_h2(v.z, v.w);
        *(uint2*)(lds8 + byte0) = h;
    }
    // ---- stage merged weights, two shifted copies: copyE[t]=Wm[t-32], copyO[u]=Wm[u-31] ----
    {
        const float* wrow = wm + c*(KK*32);
        for (int idx = tid; idx < 2*961; idx += 256) {
            const int cp = (idx >= 961);
            const int r2 = idx - cp*961;
            const int ky = r2 / 31, kx = r2 - ky*31;
            const int t = kx + (cp ? 31 : 32);
            const int byte0 = (cp ? WO_OFF : WE_OFF) + ky*192 + 2*t;
            *(_Float16*)(lds8 + byte0) = (_Float16)wrow[ky*32 + kx];
        }
    }
    __syncthreads();

    // ---- main Toeplitz-GEMM loop ----
    f32x16 acc0 = {0.f}; f32x16 acc1 = {0.f};
    const int m    = col;
    const int nn_a = m >> 4, hr = m & 15;
    const int h0a  = (hp*2 + 0) * 16;
    const int h0b  = (hp*2 + 1) * 16;
    const int acolbyte = 2*(wt*32 + 8*hi);   // + 32*cc per K-chunk

    for (int ky = 0; ky < KK; ++ky) {
        f16x8 bf[4];
        #pragma unroll
        for (int cc = 0; cc < 4; ++cc) {
            const int t0 = 16*cc + 8*hi + 31 - col;          // frag = Wm[ky, t0-32 .. t0-25]
            const int off = (t0 & 1) ? (WO_OFF + ((t0 - 1) << 1))
                                     : (WE_OFF + (t0 << 1));
            const uint32_t* wp = (const uint32_t*)(lds8 + ky*192 + off);
            u32x4 u = { wp[0], wp[1], wp[2], wp[3] };
            bf[cc] = __builtin_bit_cast(f16x8, u);
        }
        // h-tile 0
        {
            const int rl = h0a + hr + ky;
            const int sw = (rl & 14) << 3;
            const int base = nn_a*PLSZ + rl*ROWB + acolbyte;
            #pragma unroll
            for (int cc = 0; cc < 4; ++cc) {
                u64x2 u = *(const u64x2*)(lds8 + ((base + 32*cc) ^ sw));
                acc0 = __builtin_amdgcn_mfma_f32_32x32x16_f16(
                    __builtin_bit_cast(f16x8, u), bf[cc], acc0, 0, 0, 0);
            }
        }
        // h-tile 1
        {
            const int rl = h0b + hr + ky;
            const int sw = (rl & 14) << 3;
            const int base = nn_a*PLSZ + rl*ROWB + acolbyte;
            #pragma unroll
            for (int cc = 0; cc < 4; ++cc) {
                u64x2 u = *(const u64x2*)(lds8 + ((base + 32*cc) ^ sw));
                acc1 = __builtin_amdgcn_mfma_f32_32x32x16_f16(
                    __builtin_bit_cast(f16x8, u), bf[cc], acc1, 0, 0, 0);
            }
        }
    }

    // ---- epilogue: C/D layout col=lane&31, m=(reg&3)+8*(reg>>2)+4*hi ----
    const float b = bias[c];
    const int w = wt*32 + col;
    if (w < HW) {
        #pragma unroll
        for (int t = 0; t < 2; ++t) {
            const int h0 = t ? h0b : h0a;
            #pragma unroll
            for (int reg = 0; reg < 16; ++reg) {
                const int mm = (reg & 3) + 8*(reg >> 2) + 4*hi;
                const int nn = mm >> 4, hro = mm & 15;
                const int h = h0 + hro;
                if (h < HW) {
                    const float v = (t ? acc1[reg] : acc0[reg]) + b;
                    out[((size_t)((ng*2+nn)*C_CH + c))*PLANE + h*HW + w] = v;
                }
            }
        }
    }
}

extern "C" void kernel_launch(void* const* d_in, const int* in_sizes, int n_in,
                              void* d_out, int out_size, void* d_ws, size_t ws_size,
                              hipStream_t stream) {
    const float* x    = (const float*)d_in[0];
    const float* lk_w = (const float*)d_in[1];
    const float* lk_g = (const float*)d_in[2];
    const float* lk_b = (const float*)d_in[3];
    const float* lk_m = (const float*)d_in[4];
    const float* lk_v = (const float*)d_in[5];
    const float* sk_w = (const float*)d_in[6];
    const float* sk_g = (const float*)d_in[7];
    const float* sk_b = (const float*)d_in[8];
    const float* sk_m = (const float*)d_in[9];
    const float* sk_v = (const float*)d_in[10];
    float* out = (float*)d_out;

    float* wm   = (float*)d_ws;                    // 384*31*32 floats
    float* bias = wm + C_CH * (KK * 32);

    prep_weights<<<C_CH, 256, 0, stream>>>(lk_w, lk_g, lk_b, lk_m, lk_v,
                                           sk_w, sk_g, sk_b, sk_m, sk_v,
                                           wm, bias);

    dim3 grid(C_CH, 8);   // (channel, batch-pair)
    dw31_mfma<<<grid, 256, 0, stream>>>(x, wm, bias, out);
}